// Round 1
// baseline (4337.077 us; speedup 1.0000x reference)
//
#include <hip/hip_runtime.h>
#include <stdint.h>

#define DI __device__ __forceinline__

// ---- problem constants ----
constexpr int kB = 4;
constexpr int kN = 65536;
constexpr int kG = 512;   // NUM_GROUP
constexpr int kM = 64;    // GROUP_SIZE
constexpr int kE = 60;    // EMB
constexpr int GRD = 20;   // KNN grid resolution
constexpr int NCELL = GRD * GRD * GRD;
constexpr float CW = 1.0f / 20.0f;

constexpr int FPS_SUB = 8;                 // blocks per batch
constexpr int FPS_PT_T = kN / FPS_SUB / 1024; // points per thread = 8

// ---- workspace layout (bytes) ----
constexpr size_t OFF_WIN    = 0;                               // kB*kG u64 argmax slots
constexpr size_t OFF_CNT    = OFF_WIN + (size_t)kB * kG * 8;   // kB*kG u32 arrival counts
constexpr size_t OFF_CCNT   = OFF_CNT + (size_t)kB * kG * 4;   // kB*NCELL u32 cell counts
constexpr size_t ZERO_BYTES = OFF_CCNT + (size_t)kB * NCELL * 4;
constexpr size_t OFF_CSTART = ZERO_BYTES;                      // kB*(NCELL+1) u32 prefix
constexpr size_t OFF_CUR    = OFF_CSTART + (size_t)kB * (NCELL + 1) * 4; // scatter cursors
constexpr size_t OFF_W1T    = ((OFF_CUR + (size_t)kB * NCELL * 4) + 255) & ~(size_t)255;
constexpr size_t OFF_W2T    = OFF_W1T + 64 * 8 * 4;     // W1T: 64 x 8 (K padded 6->8)
constexpr size_t OFF_W3T    = OFF_W2T + 128 * 64 * 4;   // W2T: 128 x 64
constexpr size_t OFF_W4T    = OFF_W3T + 256 * 128 * 4;  // W3T: 256 x 128
constexpr size_t OFF_WPT    = OFF_W4T + 512 * 256 * 4;  // W4T: 512 x 256
constexpr size_t OFF_SORT   = ((OFF_WPT + 60 * 512 * 4) + 255) & ~(size_t)255; // kB*kN float4
constexpr size_t OFF_KIDX   = OFF_SORT + (size_t)kB * kN * 16; // kB*kG*kM u32

DI int cellof(float x) {
  int c = (int)(x * (float)GRD);
  return min(GRD - 1, max(0, c));
}
DI unsigned orderable(float f) {
  unsigned u = __float_as_uint(f);
  return (u & 0x80000000u) ? ~u : (u | 0x80000000u);
}

// =====================  zero the sync/count region  =====================
__global__ void k_zero(uint32_t* p, int nwords) {
  int i = blockIdx.x * blockDim.x + threadIdx.x;
  int st = gridDim.x * blockDim.x;
  for (; i < nwords; i += st) p[i] = 0u;
}

// =====================  pre-transpose weights  =====================
__global__ void k_prep(const float* __restrict__ W1, const float* __restrict__ W2,
                       const float* __restrict__ W3, const float* __restrict__ W4,
                       const float* __restrict__ Wp,
                       float* __restrict__ w1t, float* __restrict__ w2t,
                       float* __restrict__ w3t, float* __restrict__ w4t,
                       float* __restrict__ wpt) {
  int i0 = blockIdx.x * blockDim.x + threadIdx.x;
  int st = gridDim.x * blockDim.x;
  for (int i = i0; i < 64 * 8; i += st)   { int n = i >> 3, k = i & 7;    w1t[i] = (k < 6) ? W1[k * 64 + n] : 0.f; }
  for (int i = i0; i < 128 * 64; i += st) { int n = i >> 6, k = i & 63;   w2t[i] = W2[k * 128 + n]; }
  for (int i = i0; i < 256 * 128; i += st){ int n = i >> 7, k = i & 127;  w3t[i] = W3[k * 256 + n]; }
  for (int i = i0; i < 512 * 256; i += st){ int n = i >> 8, k = i & 255;  w4t[i] = W4[k * 512 + n]; }
  for (int i = i0; i < 60 * 512; i += st) { int n = i >> 9, k = i & 511;  wpt[i] = Wp[k * 60 + n]; }
}

// =====================  FPS  =====================
// 8 blocks per batch; xyz + running dists register-resident; device-scope
// atomicMax combine per step. Exact numpy arithmetic: (dx*dx+dy*dy)+dz*dz, rn.
__global__ __launch_bounds__(1024) void k_fps(const float* __restrict__ xyz,
                                              float* __restrict__ outC,
                                              unsigned long long* __restrict__ win,
                                              unsigned int* __restrict__ cnt) {
  const int b = blockIdx.x >> 3, sub = blockIdx.x & 7;
  const int tid = threadIdx.x;
  const float* X = xyz + (size_t)b * kN * 3;
  float px[FPS_PT_T], py[FPS_PT_T], pz[FPS_PT_T], dd[FPS_PT_T];
#pragma unroll
  for (int j = 0; j < FPS_PT_T; ++j) {
    int p = sub * (kN / FPS_SUB) + j * 1024 + tid;
    px[j] = X[3 * p]; py[j] = X[3 * p + 1]; pz[j] = X[3 * p + 2];
    dd[j] = 1e10f;
  }
  float lx = X[0], ly = X[1], lz = X[2];
  if (sub == 0 && tid == 0) {
    outC[(size_t)b * kG * 3 + 0] = lx;
    outC[(size_t)b * kG * 3 + 1] = ly;
    outC[(size_t)b * kG * 3 + 2] = lz;
  }
  __shared__ unsigned long long wres[16];
  __shared__ float sp[3];
  unsigned long long* winB = win + (size_t)b * kG;
  unsigned int* cntB = cnt + (size_t)b * kG;

  for (int it = 1; it < kG; ++it) {
    unsigned long long best = 0ull;
#pragma unroll
    for (int j = 0; j < FPS_PT_T; ++j) {
      float dx = __fsub_rn(px[j], lx);
      float dy = __fsub_rn(py[j], ly);
      float dz = __fsub_rn(pz[j], lz);
      float d = __fadd_rn(__fadd_rn(__fmul_rn(dx, dx), __fmul_rn(dy, dy)), __fmul_rn(dz, dz));
      float nd = fminf(dd[j], d);
      dd[j] = nd;
      int p = sub * (kN / FPS_SUB) + j * 1024 + tid;
      unsigned long long pk =
          ((unsigned long long)__float_as_uint(nd) << 32) | (unsigned)(0xFFFFFFFFu - (unsigned)p);
      best = (pk > best) ? pk : best;   // max dist, tie -> min index
    }
#pragma unroll
    for (int off = 32; off; off >>= 1) {
      unsigned long long o = __shfl_down(best, (unsigned)off);
      best = (o > best) ? o : best;
    }
    if ((tid & 63) == 0) wres[tid >> 6] = best;
    __syncthreads();
    if (tid == 0) {
      unsigned long long bb = wres[0];
#pragma unroll
      for (int i = 1; i < 16; ++i) bb = (wres[i] > bb) ? wres[i] : bb;
      atomicMax(winB + it, bb | (1ull << 63));
      __threadfence();
      atomicAdd(cntB + it, 1u);
      long bail = 0;
      while (__hip_atomic_load(cntB + it, __ATOMIC_ACQUIRE, __HIP_MEMORY_SCOPE_AGENT) < (unsigned)FPS_SUB) {
        __builtin_amdgcn_s_sleep(1);
        if (++bail > 100000000L) break;  // never in practice
      }
      unsigned long long w = __hip_atomic_load(winB + it, __ATOMIC_ACQUIRE, __HIP_MEMORY_SCOPE_AGENT);
      int wi = (int)(0xFFFFFFFFu - (unsigned)(w & 0xFFFFFFFFu));
      float wx = X[3 * wi], wy = X[3 * wi + 1], wz = X[3 * wi + 2];
      sp[0] = wx; sp[1] = wy; sp[2] = wz;
      if (sub == 0) {
        outC[((size_t)b * kG + it) * 3 + 0] = wx;
        outC[((size_t)b * kG + it) * 3 + 1] = wy;
        outC[((size_t)b * kG + it) * 3 + 2] = wz;
      }
    }
    __syncthreads();
    lx = sp[0]; ly = sp[1]; lz = sp[2];
  }
}

// =====================  grid build  =====================
__global__ void k_cellcount(const float* __restrict__ xyz, uint32_t* __restrict__ ccnt) {
  int i = blockIdx.x * blockDim.x + threadIdx.x;
  int st = gridDim.x * blockDim.x;
  for (; i < kB * kN; i += st) {
    int b = i >> 16, p = i & (kN - 1);
    const float* q = xyz + ((size_t)b * kN + p) * 3;
    int cid = (cellof(q[2]) * GRD + cellof(q[1])) * GRD + cellof(q[0]);
    atomicAdd(&ccnt[b * NCELL + cid], 1u);
  }
}

__global__ void k_scan(const uint32_t* __restrict__ ccnt, uint32_t* __restrict__ cstart,
                       uint32_t* __restrict__ cur) {
  int b = blockIdx.x, tid = threadIdx.x;
  const uint32_t* cc = ccnt + (size_t)b * NCELL;
  uint32_t* cs = cstart + (size_t)b * (NCELL + 1);
  uint32_t* cu = cur + (size_t)b * NCELL;
  __shared__ uint32_t part[256];
  const int chunk = 32;  // 256*32 >= 8000
  int c0 = tid * chunk;
  uint32_t s = 0;
  for (int i = 0; i < chunk; ++i) { int c = c0 + i; if (c < NCELL) s += cc[c]; }
  part[tid] = s;
  __syncthreads();
  for (int off = 1; off < 256; off <<= 1) {
    uint32_t add = (tid >= off) ? part[tid - off] : 0u;
    __syncthreads();
    part[tid] += add;
    __syncthreads();
  }
  uint32_t run = part[tid] - s;  // exclusive prefix
  for (int i = 0; i < chunk; ++i) {
    int c = c0 + i;
    if (c < NCELL) { cs[c] = run; cu[c] = run; run += cc[c]; }
  }
  if (tid == 255) cs[NCELL] = run;
}

__global__ void k_scatter(const float* __restrict__ xyz, uint32_t* __restrict__ cur,
                          float4* __restrict__ sorted) {
  int i = blockIdx.x * blockDim.x + threadIdx.x;
  int st = gridDim.x * blockDim.x;
  for (; i < kB * kN; i += st) {
    int b = i >> 16, p = i & (kN - 1);
    const float* q = xyz + ((size_t)b * kN + p) * 3;
    float x = q[0], y = q[1], z = q[2];
    int cid = (cellof(z) * GRD + cellof(y)) * GRD + cellof(x);
    uint32_t pos = atomicAdd(&cur[b * NCELL + cid], 1u);
    sorted[(size_t)b * kN + pos] = make_float4(x, y, z, __uint_as_float((unsigned)p));
  }
}

// =====================  KNN (expanding box + exact re-rank + bitonic)  =====================
constexpr int CAP = 8192;

DI void bitonic(unsigned long long* a, int n, int tid) {
  for (int k = 2; k <= n; k <<= 1)
    for (int j = k >> 1; j > 0; j >>= 1) {
      __syncthreads();
      for (int i = tid; i < n; i += 256) {
        int ix = i ^ j;
        if (ix > i) {
          unsigned long long x = a[i], y = a[ix];
          bool up = ((i & k) == 0);
          if ((x > y) == up) { a[i] = y; a[ix] = x; }
        }
      }
    }
  __syncthreads();
}

__global__ __launch_bounds__(256) void k_knn(const float4* __restrict__ sorted,
                                             const uint32_t* __restrict__ cstart,
                                             const float* __restrict__ outC,
                                             uint32_t* __restrict__ kidx) {
  const int bi = blockIdx.x;
  const int b = (bi & 7) >> 1;                    // XCD-pair per batch for L2 locality
  const int g = ((bi >> 3) << 1) | (bi & 1);
  const int tid = threadIdx.x;
  __shared__ unsigned long long cand[CAP];
  __shared__ int nC;
  const float cx = outC[((size_t)b * kG + g) * 3 + 0];
  const float cy = outC[((size_t)b * kG + g) * 3 + 1];
  const float cz = outC[((size_t)b * kG + g) * 3 + 2];
  const float nc = __fadd_rn(__fadd_rn(__fmul_rn(cx, cx), __fmul_rn(cy, cy)), __fmul_rn(cz, cz));
  const float4* SP = sorted + (size_t)b * kN;
  const uint32_t* CS = cstart + (size_t)b * (NCELL + 1);
  const int ccx = cellof(cx), ccy = cellof(cy), ccz = cellof(cz);
  if (tid == 0) nC = 0;
  __syncthreads();
  int plox = 1, phix = 0, ploy = 1, phiy = 0, ploz = 1, phiz = 0;  // empty prev box
  for (int r = 1; r <= GRD; ++r) {
    int lox = max(0, ccx - r), hix = min(GRD - 1, ccx + r);
    int loy = max(0, ccy - r), hiy = min(GRD - 1, ccy + r);
    int loz = max(0, ccz - r), hiz = min(GRD - 1, ccz + r);
    for (int z = loz; z <= hiz; ++z)
      for (int y = loy; y <= hiy; ++y) {
        bool rowPrev = (r > 1) && (z >= ploz && z <= phiz && y >= ploy && y <= phiy);
        for (int s = 0; s < 2; ++s) {
          int xa, xb;
          if (!rowPrev) { if (s) break; xa = lox; xb = hix; }
          else if (s == 0) { xa = lox; xb = plox - 1; }
          else { xa = phix + 1; xb = hix; }
          if (xa > xb) continue;
          int c0 = (z * GRD + y) * GRD + xa;
          int i0 = CS[c0];
          int i1 = CS[(z * GRD + y) * GRD + xb + 1];
          for (int i = i0 + tid; i < i1; i += 256) {
            float4 pt = SP[i];
            float npn = __fadd_rn(__fadd_rn(__fmul_rn(pt.x, pt.x), __fmul_rn(pt.y, pt.y)),
                                  __fmul_rn(pt.z, pt.z));
            float dot = __fadd_rn(__fadd_rn(__fmul_rn(cx, pt.x), __fmul_rn(cy, pt.y)),
                                  __fmul_rn(cz, pt.z));
            float sq = __fsub_rn(__fadd_rn(nc, npn), __fmul_rn(2.0f, dot));
            unsigned key = orderable(sq);
            int pos = atomicAdd(&nC, 1);
            if (pos < CAP)
              cand[pos] = ((unsigned long long)key << 32) | (unsigned)__float_as_uint(pt.w);
          }
        }
      }
    __syncthreads();
    int n = min(nC, CAP);
    float rc = 1e30f;
    if (lox > 0) rc = fminf(rc, cx - (float)lox * CW);
    if (hix < GRD - 1) rc = fminf(rc, (float)(hix + 1) * CW - cx);
    if (loy > 0) rc = fminf(rc, cy - (float)loy * CW);
    if (hiy < GRD - 1) rc = fminf(rc, (float)(hiy + 1) * CW - cy);
    if (loz > 0) rc = fminf(rc, cz - (float)loz * CW);
    if (hiz < GRD - 1) rc = fminf(rc, (float)(hiz + 1) * CW - cz);
    float r2 = (rc >= 1e29f) ? 3.0e38f : rc * rc * (1.0f - 1e-5f);
    unsigned keyR = orderable(r2);
    bool done = false;
    if (n >= kM) {
      int np2 = 1;
      while (np2 < n) np2 <<= 1;
      for (int i = n + tid; i < np2; i += 256) cand[i] = ~0ull;
      bitonic(cand, np2, tid);  // starts and ends with __syncthreads
      unsigned k63 = (unsigned)(cand[kM - 1] >> 32);
      done = (k63 <= keyR);
      if (tid == 0) nC = n;  // clamp after potential overflow
    }
    __syncthreads();
    if (done) break;
    plox = lox; phix = hix; ploy = loy; phiy = hiy; ploz = loz; phiz = hiz;
  }
  if (tid < kM)
    kidx[((size_t)b * kG + g) * kM + tid] = (uint32_t)(cand[tid] & 0xFFFFFFFFu);
}

// =====================  fused per-group MLP (f32, round-0 baseline)  =====================
template <int K, int NN, int TJ, int TP, bool LAST>
DI void layer(const float* __restrict__ WT, const float* __restrict__ bias,
              const float* __restrict__ As, float* __restrict__ Os,
              unsigned int* __restrict__ maxb, int tid) {
  constexpr int NJ = NN / TJ, NPt = kM / TP;
  for (int t = tid; t < NJ * NPt; t += 256) {
    int jt = t % NJ, pt = t / NJ;
    float acc[TP][TJ];
    const float* wbase = WT + (size_t)(jt * TJ) * K;
#pragma unroll
    for (int pp = 0; pp < TP; ++pp)
#pragma unroll
      for (int jj = 0; jj < TJ; ++jj) acc[pp][jj] = bias[jt * TJ + jj];
#pragma unroll 4
    for (int k = 0; k < K; ++k) {
      float wv[TJ], av[TP];
#pragma unroll
      for (int jj = 0; jj < TJ; ++jj) wv[jj] = wbase[(size_t)jj * K + k];
#pragma unroll
      for (int pp = 0; pp < TP; ++pp) av[pp] = As[(pt * TP + pp) * K + k];
#pragma unroll
      for (int pp = 0; pp < TP; ++pp)
#pragma unroll
        for (int jj = 0; jj < TJ; ++jj) acc[pp][jj] = fmaf(av[pp], wv[jj], acc[pp][jj]);
    }
    if constexpr (!LAST) {
#pragma unroll
      for (int pp = 0; pp < TP; ++pp)
#pragma unroll
        for (int jj = 0; jj < TJ; ++jj)
          Os[(pt * TP + pp) * NN + jt * TJ + jj] = fmaxf(acc[pp][jj], 0.f);
    } else {
#pragma unroll
      for (int jj = 0; jj < TJ; ++jj) {
        float mx = 0.f;
#pragma unroll
        for (int pp = 0; pp < TP; ++pp) mx = fmaxf(mx, acc[pp][jj]);
        atomicMax(&maxb[jt * TJ + jj], __float_as_uint(fmaxf(mx, 0.f)));
      }
    }
  }
}

__global__ __launch_bounds__(256) void k_mlp(
    const float* __restrict__ xyz, const float* __restrict__ color,
    const float* __restrict__ outC, const uint32_t* __restrict__ kidx,
    const float* __restrict__ w1t, const float* __restrict__ w2t,
    const float* __restrict__ w3t, const float* __restrict__ w4t,
    const float* __restrict__ wpt,
    const float* __restrict__ b1, const float* __restrict__ b2,
    const float* __restrict__ b3, const float* __restrict__ b4,
    const float* __restrict__ bp, float* __restrict__ outE) {
  const int bi = blockIdx.x;
  const int b = (bi & 7) >> 1;
  const int g = ((bi >> 3) << 1) | (bi & 1);
  const int tid = threadIdx.x;
  __shared__ float bufA[64 * 128];   // feats(64x8), A2(64x128)
  __shared__ float bufB[64 * 256];   // A1(64x64), A3(64x256)
  __shared__ unsigned int maxb[512];
  __shared__ float psum[240];
  __shared__ float cen[3];
  if (tid < 3) cen[tid] = outC[((size_t)b * kG + g) * 3 + tid];
  maxb[tid] = 0u;
  maxb[tid + 256] = 0u;
  __syncthreads();
  if (tid < kM) {
    uint32_t p = kidx[((size_t)b * kG + g) * kM + tid];
    const float* xp = xyz + ((size_t)b * kN + p) * 3;
    const float* cp = color + ((size_t)b * kN + p) * 3;
    bufA[tid * 8 + 0] = __fsub_rn(xp[0], cen[0]);
    bufA[tid * 8 + 1] = __fsub_rn(xp[1], cen[1]);
    bufA[tid * 8 + 2] = __fsub_rn(xp[2], cen[2]);
    bufA[tid * 8 + 3] = cp[0];
    bufA[tid * 8 + 4] = cp[1];
    bufA[tid * 8 + 5] = cp[2];
    bufA[tid * 8 + 6] = 0.f;
    bufA[tid * 8 + 7] = 0.f;
  }
  __syncthreads();
  layer<8, 64, 2, 2, false>(w1t, b1, bufA, bufB, nullptr, tid);
  __syncthreads();
  layer<64, 128, 4, 4, false>(w2t, b2, bufB, bufA, nullptr, tid);
  __syncthreads();
  layer<128, 256, 8, 8, false>(w3t, b3, bufA, bufB, nullptr, tid);
  __syncthreads();
  layer<256, 512, 8, 8, true>(w4t, b4, bufB, nullptr, maxb, tid);
  __syncthreads();
  if (tid < 240) {
    int j = tid >> 2, q = tid & 3;
    const float* w = wpt + (size_t)j * 512 + q * 128;
    float s = 0.f;
#pragma unroll 4
    for (int k = 0; k < 128; ++k) s = fmaf(__uint_as_float(maxb[q * 128 + k]), w[k], s);
    psum[tid] = s;
  }
  __syncthreads();
  if (tid < kE) {
    float e = __fadd_rn(__fadd_rn(psum[tid * 4 + 0], psum[tid * 4 + 1]),
                        __fadd_rn(psum[tid * 4 + 2], psum[tid * 4 + 3])) + bp[tid];
    outE[((size_t)b * kG + g) * kE + tid] = e;
  }
}

// =====================  launch  =====================
extern "C" void kernel_launch(void* const* d_in, const int* in_sizes, int n_in,
                              void* d_out, int out_size, void* d_ws, size_t ws_size,
                              hipStream_t stream) {
  (void)in_sizes; (void)n_in; (void)out_size; (void)ws_size;
  const float* xyz = (const float*)d_in[0];
  const float* color = (const float*)d_in[1];
  const float* W1 = (const float*)d_in[2];
  const float* b1 = (const float*)d_in[3];
  const float* W2 = (const float*)d_in[4];
  const float* b2 = (const float*)d_in[5];
  const float* W3 = (const float*)d_in[6];
  const float* b3 = (const float*)d_in[7];
  const float* W4 = (const float*)d_in[8];
  const float* b4 = (const float*)d_in[9];
  const float* Wp = (const float*)d_in[10];
  const float* bp = (const float*)d_in[11];

  char* ws = (char*)d_ws;
  auto win = (unsigned long long*)(ws + OFF_WIN);
  auto cnt = (unsigned int*)(ws + OFF_CNT);
  auto ccnt = (uint32_t*)(ws + OFF_CCNT);
  auto cstart = (uint32_t*)(ws + OFF_CSTART);
  auto cur = (uint32_t*)(ws + OFF_CUR);
  auto w1t = (float*)(ws + OFF_W1T);
  auto w2t = (float*)(ws + OFF_W2T);
  auto w3t = (float*)(ws + OFF_W3T);
  auto w4t = (float*)(ws + OFF_W4T);
  auto wpt = (float*)(ws + OFF_WPT);
  auto sorted = (float4*)(ws + OFF_SORT);
  auto kidx = (uint32_t*)(ws + OFF_KIDX);

  float* outE = (float*)d_out;
  float* outC = outE + (size_t)kB * kG * kE;

  k_zero<<<64, 256, 0, stream>>>((uint32_t*)ws, (int)(ZERO_BYTES / 4));
  k_prep<<<256, 256, 0, stream>>>(W1, W2, W3, W4, Wp, w1t, w2t, w3t, w4t, wpt);
  k_fps<<<kB * FPS_SUB, 1024, 0, stream>>>(xyz, outC, win, cnt);
  k_cellcount<<<512, 256, 0, stream>>>(xyz, ccnt);
  k_scan<<<kB, 256, 0, stream>>>(ccnt, cstart, cur);
  k_scatter<<<512, 256, 0, stream>>>(xyz, cur, sorted);
  k_knn<<<kB * kG, 256, 0, stream>>>(sorted, cstart, outC, kidx);
  k_mlp<<<kB * kG, 256, 0, stream>>>(xyz, color, outC, kidx, w1t, w2t, w3t, w4t, wpt,
                                     b1, b2, b3, b4, bp, outE);
}

// Round 2
// 2001.000 us; speedup vs baseline: 2.1675x; 2.1675x over previous
//
#include <hip/hip_runtime.h>
#include <stdint.h>

#define DI __device__ __forceinline__

typedef _Float16 f16x8 __attribute__((ext_vector_type(8)));
typedef float f32x4 __attribute__((ext_vector_type(4)));

// ---- problem constants ----
constexpr int kB = 4;
constexpr int kN = 65536;
constexpr int kG = 512;   // NUM_GROUP
constexpr int kM = 64;    // GROUP_SIZE
constexpr int kE = 60;    // EMB
constexpr int GRD = 20;   // KNN grid resolution
constexpr int NCELL = GRD * GRD * GRD;
constexpr float CW = 1.0f / 20.0f;

constexpr int FPS_SUB = 8;                 // blocks per batch
constexpr int FPS_PT_T = kN / FPS_SUB / 1024; // points per thread = 8

// ---- workspace layout (bytes) ----
constexpr size_t OFF_WIN    = 0;                               // kB*kG u64 argmax slots
constexpr size_t OFF_CNT    = OFF_WIN + (size_t)kB * kG * 8;   // kB*kG u32 arrival counts
constexpr size_t OFF_CCNT   = OFF_CNT + (size_t)kB * kG * 4;   // kB*NCELL u32 cell counts
constexpr size_t ZERO_BYTES = OFF_CCNT + (size_t)kB * NCELL * 4;
constexpr size_t OFF_CSTART = ZERO_BYTES;                      // kB*(NCELL+1) u32 prefix
constexpr size_t OFF_CUR    = OFF_CSTART + (size_t)kB * (NCELL + 1) * 4; // scatter cursors
// swizzled f16 weights (B-fragment order) + f32 transposed Wp
constexpr size_t OFF_SW1    = ((OFF_CUR + (size_t)kB * NCELL * 4) + 255) & ~(size_t)255;
constexpr size_t OFF_SW2    = OFF_SW1 + 2048 * 2;    // L1: 4nt*1ks*512
constexpr size_t OFF_SW3    = OFF_SW2 + 8192 * 2;    // L2: 8nt*2ks*512
constexpr size_t OFF_SW4    = OFF_SW3 + 32768 * 2;   // L3: 16nt*4ks*512
constexpr size_t OFF_WPT    = OFF_SW4 + 131072 * 2;  // L4: 32nt*8ks*512
constexpr size_t OFF_SORT   = ((OFF_WPT + 60 * 512 * 4) + 255) & ~(size_t)255; // kB*kN float4
constexpr size_t OFF_KIDX   = OFF_SORT + (size_t)kB * kN * 16; // kB*kG*kM u32

DI int cellof(float x) {
  int c = (int)(x * (float)GRD);
  return min(GRD - 1, max(0, c));
}
DI unsigned orderable(float f) {
  unsigned u = __float_as_uint(f);
  return (u & 0x80000000u) ? ~u : (u | 0x80000000u);
}

// =====================  zero the sync/count region  =====================
__global__ void k_zero(uint32_t* p, int nwords) {
  int i = blockIdx.x * blockDim.x + threadIdx.x;
  int st = gridDim.x * blockDim.x;
  for (; i < nwords; i += st) p[i] = 0u;
}

// =====================  weight prep: B-fragment swizzle (f16) + WpT  =====================
// sw layout per layer: [(nt*nks + ks)*64 + lane]*8 + j  ->  W[k][n], k=ks*32+(lane>>4)*8+j,
// n=nt*16+(lane&15). Zero-pad k >= Kreal.
DI void swz(const float* __restrict__ W, _Float16* __restrict__ sw,
            int total, int nks, int Kreal, int N, int i0, int st) {
  for (int i = i0; i < total; i += st) {
    int j = i & 7, lane = (i >> 3) & 63, rest = i >> 9;
    int ks = rest % nks, nt = rest / nks;
    int k = ks * 32 + ((lane >> 4) << 3) + j;
    int n = nt * 16 + (lane & 15);
    sw[i] = (_Float16)((k < Kreal) ? W[k * N + n] : 0.f);
  }
}

__global__ void k_prep(const float* __restrict__ W1, const float* __restrict__ W2,
                       const float* __restrict__ W3, const float* __restrict__ W4,
                       const float* __restrict__ Wp,
                       _Float16* __restrict__ sw1, _Float16* __restrict__ sw2,
                       _Float16* __restrict__ sw3, _Float16* __restrict__ sw4,
                       float* __restrict__ wpt) {
  int i0 = blockIdx.x * blockDim.x + threadIdx.x;
  int st = gridDim.x * blockDim.x;
  swz(W1, sw1, 2048, 1, 6, 64, i0, st);
  swz(W2, sw2, 8192, 2, 64, 128, i0, st);
  swz(W3, sw3, 32768, 4, 128, 256, i0, st);
  swz(W4, sw4, 131072, 8, 256, 512, i0, st);
  for (int i = i0; i < 60 * 512; i += st) { int n = i >> 9, k = i & 511; wpt[i] = Wp[k * 60 + n]; }
}

// =====================  FPS  =====================
__global__ __launch_bounds__(1024) void k_fps(const float* __restrict__ xyz,
                                              float* __restrict__ outC,
                                              unsigned long long* __restrict__ win,
                                              unsigned int* __restrict__ cnt) {
  const int b = blockIdx.x >> 3, sub = blockIdx.x & 7;
  const int tid = threadIdx.x;
  const float* X = xyz + (size_t)b * kN * 3;
  float px[FPS_PT_T], py[FPS_PT_T], pz[FPS_PT_T], dd[FPS_PT_T];
#pragma unroll
  for (int j = 0; j < FPS_PT_T; ++j) {
    int p = sub * (kN / FPS_SUB) + j * 1024 + tid;
    px[j] = X[3 * p]; py[j] = X[3 * p + 1]; pz[j] = X[3 * p + 2];
    dd[j] = 1e10f;
  }
  float lx = X[0], ly = X[1], lz = X[2];
  if (sub == 0 && tid == 0) {
    outC[(size_t)b * kG * 3 + 0] = lx;
    outC[(size_t)b * kG * 3 + 1] = ly;
    outC[(size_t)b * kG * 3 + 2] = lz;
  }
  __shared__ unsigned long long wres[16];
  __shared__ float sp[3];
  unsigned long long* winB = win + (size_t)b * kG;
  unsigned int* cntB = cnt + (size_t)b * kG;

  for (int it = 1; it < kG; ++it) {
    unsigned long long best = 0ull;
#pragma unroll
    for (int j = 0; j < FPS_PT_T; ++j) {
      float dx = __fsub_rn(px[j], lx);
      float dy = __fsub_rn(py[j], ly);
      float dz = __fsub_rn(pz[j], lz);
      float d = __fadd_rn(__fadd_rn(__fmul_rn(dx, dx), __fmul_rn(dy, dy)), __fmul_rn(dz, dz));
      float nd = fminf(dd[j], d);
      dd[j] = nd;
      int p = sub * (kN / FPS_SUB) + j * 1024 + tid;
      unsigned long long pk =
          ((unsigned long long)__float_as_uint(nd) << 32) | (unsigned)(0xFFFFFFFFu - (unsigned)p);
      best = (pk > best) ? pk : best;   // max dist, tie -> min index
    }
#pragma unroll
    for (int off = 32; off; off >>= 1) {
      unsigned long long o = __shfl_down(best, (unsigned)off);
      best = (o > best) ? o : best;
    }
    if ((tid & 63) == 0) wres[tid >> 6] = best;
    __syncthreads();
    if (tid == 0) {
      unsigned long long bb = wres[0];
#pragma unroll
      for (int i = 1; i < 16; ++i) bb = (wres[i] > bb) ? wres[i] : bb;
      atomicMax(winB + it, bb | (1ull << 63));
      __threadfence();
      atomicAdd(cntB + it, 1u);
      long bail = 0;
      while (__hip_atomic_load(cntB + it, __ATOMIC_ACQUIRE, __HIP_MEMORY_SCOPE_AGENT) < (unsigned)FPS_SUB) {
        __builtin_amdgcn_s_sleep(1);
        if (++bail > 100000000L) break;
      }
      unsigned long long w = __hip_atomic_load(winB + it, __ATOMIC_ACQUIRE, __HIP_MEMORY_SCOPE_AGENT);
      int wi = (int)(0xFFFFFFFFu - (unsigned)(w & 0xFFFFFFFFu));
      float wx = X[3 * wi], wy = X[3 * wi + 1], wz = X[3 * wi + 2];
      sp[0] = wx; sp[1] = wy; sp[2] = wz;
      if (sub == 0) {
        outC[((size_t)b * kG + it) * 3 + 0] = wx;
        outC[((size_t)b * kG + it) * 3 + 1] = wy;
        outC[((size_t)b * kG + it) * 3 + 2] = wz;
      }
    }
    __syncthreads();
    lx = sp[0]; ly = sp[1]; lz = sp[2];
  }
}

// =====================  grid build  =====================
__global__ void k_cellcount(const float* __restrict__ xyz, uint32_t* __restrict__ ccnt) {
  int i = blockIdx.x * blockDim.x + threadIdx.x;
  int st = gridDim.x * blockDim.x;
  for (; i < kB * kN; i += st) {
    int b = i >> 16, p = i & (kN - 1);
    const float* q = xyz + ((size_t)b * kN + p) * 3;
    int cid = (cellof(q[2]) * GRD + cellof(q[1])) * GRD + cellof(q[0]);
    atomicAdd(&ccnt[b * NCELL + cid], 1u);
  }
}

__global__ void k_scan(const uint32_t* __restrict__ ccnt, uint32_t* __restrict__ cstart,
                       uint32_t* __restrict__ cur) {
  int b = blockIdx.x, tid = threadIdx.x;
  const uint32_t* cc = ccnt + (size_t)b * NCELL;
  uint32_t* cs = cstart + (size_t)b * (NCELL + 1);
  uint32_t* cu = cur + (size_t)b * NCELL;
  __shared__ uint32_t part[256];
  const int chunk = 32;
  int c0 = tid * chunk;
  uint32_t s = 0;
  for (int i = 0; i < chunk; ++i) { int c = c0 + i; if (c < NCELL) s += cc[c]; }
  part[tid] = s;
  __syncthreads();
  for (int off = 1; off < 256; off <<= 1) {
    uint32_t add = (tid >= off) ? part[tid - off] : 0u;
    __syncthreads();
    part[tid] += add;
    __syncthreads();
  }
  uint32_t run = part[tid] - s;  // exclusive prefix
  for (int i = 0; i < chunk; ++i) {
    int c = c0 + i;
    if (c < NCELL) { cs[c] = run; cu[c] = run; run += cc[c]; }
  }
  if (tid == 255) cs[NCELL] = run;
}

__global__ void k_scatter(const float* __restrict__ xyz, uint32_t* __restrict__ cur,
                          float4* __restrict__ sorted) {
  int i = blockIdx.x * blockDim.x + threadIdx.x;
  int st = gridDim.x * blockDim.x;
  for (; i < kB * kN; i += st) {
    int b = i >> 16, p = i & (kN - 1);
    const float* q = xyz + ((size_t)b * kN + p) * 3;
    float x = q[0], y = q[1], z = q[2];
    int cid = (cellof(z) * GRD + cellof(y)) * GRD + cellof(x);
    uint32_t pos = atomicAdd(&cur[b * NCELL + cid], 1u);
    sorted[(size_t)b * kN + pos] = make_float4(x, y, z, __uint_as_float((unsigned)p));
  }
}

// =====================  KNN (expanding box + exact re-rank + bitonic)  =====================
constexpr int CAP = 8192;

DI void bitonic(unsigned long long* a, int n, int tid) {
  for (int k = 2; k <= n; k <<= 1)
    for (int j = k >> 1; j > 0; j >>= 1) {
      __syncthreads();
      for (int i = tid; i < n; i += 256) {
        int ix = i ^ j;
        if (ix > i) {
          unsigned long long x = a[i], y = a[ix];
          bool up = ((i & k) == 0);
          if ((x > y) == up) { a[i] = y; a[ix] = x; }
        }
      }
    }
  __syncthreads();
}

__global__ __launch_bounds__(256) void k_knn(const float4* __restrict__ sorted,
                                             const uint32_t* __restrict__ cstart,
                                             const float* __restrict__ outC,
                                             uint32_t* __restrict__ kidx) {
  const int bi = blockIdx.x;
  const int b = (bi & 7) >> 1;
  const int g = ((bi >> 3) << 1) | (bi & 1);
  const int tid = threadIdx.x;
  __shared__ unsigned long long cand[CAP];
  __shared__ int nC;
  const float cx = outC[((size_t)b * kG + g) * 3 + 0];
  const float cy = outC[((size_t)b * kG + g) * 3 + 1];
  const float cz = outC[((size_t)b * kG + g) * 3 + 2];
  const float nc = __fadd_rn(__fadd_rn(__fmul_rn(cx, cx), __fmul_rn(cy, cy)), __fmul_rn(cz, cz));
  const float4* SP = sorted + (size_t)b * kN;
  const uint32_t* CS = cstart + (size_t)b * (NCELL + 1);
  const int ccx = cellof(cx), ccy = cellof(cy), ccz = cellof(cz);
  if (tid == 0) nC = 0;
  __syncthreads();
  int plox = 1, phix = 0, ploy = 1, phiy = 0, ploz = 1, phiz = 0;
  for (int r = 1; r <= GRD; ++r) {
    int lox = max(0, ccx - r), hix = min(GRD - 1, ccx + r);
    int loy = max(0, ccy - r), hiy = min(GRD - 1, ccy + r);
    int loz = max(0, ccz - r), hiz = min(GRD - 1, ccz + r);
    for (int z = loz; z <= hiz; ++z)
      for (int y = loy; y <= hiy; ++y) {
        bool rowPrev = (r > 1) && (z >= ploz && z <= phiz && y >= ploy && y <= phiy);
        for (int s = 0; s < 2; ++s) {
          int xa, xb;
          if (!rowPrev) { if (s) break; xa = lox; xb = hix; }
          else if (s == 0) { xa = lox; xb = plox - 1; }
          else { xa = phix + 1; xb = hix; }
          if (xa > xb) continue;
          int c0 = (z * GRD + y) * GRD + xa;
          int i0 = CS[c0];
          int i1 = CS[(z * GRD + y) * GRD + xb + 1];
          for (int i = i0 + tid; i < i1; i += 256) {
            float4 pt = SP[i];
            float npn = __fadd_rn(__fadd_rn(__fmul_rn(pt.x, pt.x), __fmul_rn(pt.y, pt.y)),
                                  __fmul_rn(pt.z, pt.z));
            float dot = __fadd_rn(__fadd_rn(__fmul_rn(cx, pt.x), __fmul_rn(cy, pt.y)),
                                  __fmul_rn(cz, pt.z));
            float sq = __fsub_rn(__fadd_rn(nc, npn), __fmul_rn(2.0f, dot));
            unsigned key = orderable(sq);
            int pos = atomicAdd(&nC, 1);
            if (pos < CAP)
              cand[pos] = ((unsigned long long)key << 32) | (unsigned)__float_as_uint(pt.w);
          }
        }
      }
    __syncthreads();
    int n = min(nC, CAP);
    float rc = 1e30f;
    if (lox > 0) rc = fminf(rc, cx - (float)lox * CW);
    if (hix < GRD - 1) rc = fminf(rc, (float)(hix + 1) * CW - cx);
    if (loy > 0) rc = fminf(rc, cy - (float)loy * CW);
    if (hiy < GRD - 1) rc = fminf(rc, (float)(hiy + 1) * CW - cy);
    if (loz > 0) rc = fminf(rc, cz - (float)loz * CW);
    if (hiz < GRD - 1) rc = fminf(rc, (float)(hiz + 1) * CW - cz);
    float r2 = (rc >= 1e29f) ? 3.0e38f : rc * rc * (1.0f - 1e-5f);
    unsigned keyR = orderable(r2);
    bool done = false;
    if (n >= kM) {
      int np2 = 1;
      while (np2 < n) np2 <<= 1;
      for (int i = n + tid; i < np2; i += 256) cand[i] = ~0ull;
      bitonic(cand, np2, tid);
      unsigned k63 = (unsigned)(cand[kM - 1] >> 32);
      done = (k63 <= keyR);
      if (tid == 0) nC = n;
    }
    __syncthreads();
    if (done) break;
    plox = lox; phix = hix; ploy = loy; phiy = hiy; ploz = loz; phiz = hiz;
  }
  if (tid < kM)
    kidx[((size_t)b * kG + g) * kM + tid] = (uint32_t)(cand[tid] & 0xFFFFFFFFu);
}

// =====================  fused per-group MLP — f16 MFMA  =====================
// One block = one group. 4 waves; wave w owns cols [w*N/4, (w+1)*N/4).
// A-frag: lane holds X[m16 + (lane&15)][ks*32 + (lane>>4)*8 + j]  (ds_read_b128)
// B-frag: lane holds W[ks*32 + (lane>>4)*8 + j][n0 + (lane&15)]   (pre-swizzled, 16B global)
// D: lane reg r = D[(lane>>4)*4 + r][lane&15]

template <int Kdim, int Ndim, int SIN, int SOUT>
DI void mfma_layer(const _Float16* __restrict__ Xin, _Float16* __restrict__ Xout,
                   const _Float16* __restrict__ Wsw, const float* __restrict__ bias,
                   int wave, int lane) {
  constexpr int NKS = Kdim / 32;
  constexpr int NTW = Ndim / 64;               // n-tiles per wave
  constexpr int CH = (NTW < 4) ? NTW : 4;      // acc chunk
  const int quad = lane >> 4, l16 = lane & 15;
  for (int c0 = 0; c0 < NTW; c0 += CH) {
    f32x4 acc[CH][4];
#pragma unroll
    for (int nt = 0; nt < CH; ++nt) {
      float bv = bias[wave * (Ndim / 4) + (c0 + nt) * 16 + l16];
#pragma unroll
      for (int m = 0; m < 4; ++m) acc[nt][m] = {bv, bv, bv, bv};
    }
#pragma unroll
    for (int ks = 0; ks < NKS; ++ks) {
      f16x8 af[4];
#pragma unroll
      for (int m = 0; m < 4; ++m)
        af[m] = *(const f16x8*)(Xin + (m * 16 + l16) * SIN + ks * 32 + quad * 8);
#pragma unroll
      for (int nt = 0; nt < CH; ++nt) {
        int ntg = wave * NTW + c0 + nt;
        f16x8 bf = *(const f16x8*)(Wsw + ((size_t)(ntg * NKS + ks) * 64 + lane) * 8);
#pragma unroll
        for (int m = 0; m < 4; ++m)
          acc[nt][m] = __builtin_amdgcn_mfma_f32_16x16x32_f16(af[m], bf, acc[nt][m], 0, 0, 0);
      }
    }
#pragma unroll
    for (int nt = 0; nt < CH; ++nt) {
      int col = wave * (Ndim / 4) + (c0 + nt) * 16 + l16;
#pragma unroll
      for (int m = 0; m < 4; ++m)
#pragma unroll
        for (int r = 0; r < 4; ++r) {
          int row = m * 16 + quad * 4 + r;
          Xout[row * SOUT + col] = (_Float16)fmaxf(acc[nt][m][r], 0.f);
        }
    }
  }
}

DI void mfma_layer4(const _Float16* __restrict__ Xin, const _Float16* __restrict__ Wsw,
                    const float* __restrict__ bias, float* __restrict__ maxv,
                    int wave, int lane) {
  constexpr int SIN = 264, NKS = 8, NTW = 8, CH = 4;
  const int quad = lane >> 4, l16 = lane & 15;
  for (int c0 = 0; c0 < NTW; c0 += CH) {
    f32x4 acc[CH][4];
#pragma unroll
    for (int nt = 0; nt < CH; ++nt) {
      float bv = bias[wave * 128 + (c0 + nt) * 16 + l16];
#pragma unroll
      for (int m = 0; m < 4; ++m) acc[nt][m] = {bv, bv, bv, bv};
    }
#pragma unroll
    for (int ks = 0; ks < NKS; ++ks) {
      f16x8 af[4];
#pragma unroll
      for (int m = 0; m < 4; ++m)
        af[m] = *(const f16x8*)(Xin + (m * 16 + l16) * SIN + ks * 32 + quad * 8);
#pragma unroll
      for (int nt = 0; nt < CH; ++nt) {
        int ntg = wave * NTW + c0 + nt;
        f16x8 bf = *(const f16x8*)(Wsw + ((size_t)(ntg * NKS + ks) * 64 + lane) * 8);
#pragma unroll
        for (int m = 0; m < 4; ++m)
          acc[nt][m] = __builtin_amdgcn_mfma_f32_16x16x32_f16(af[m], bf, acc[nt][m], 0, 0, 0);
      }
    }
#pragma unroll
    for (int nt = 0; nt < CH; ++nt) {
      float mx = 0.f;  // relu folded into max
#pragma unroll
      for (int m = 0; m < 4; ++m)
#pragma unroll
        for (int r = 0; r < 4; ++r) mx = fmaxf(mx, acc[nt][m][r]);
      mx = fmaxf(mx, __shfl_xor(mx, 16, 64));
      mx = fmaxf(mx, __shfl_xor(mx, 32, 64));
      if (quad == 0) maxv[wave * 128 + (c0 + nt) * 16 + l16] = mx;
    }
  }
}

__global__ __launch_bounds__(256) void k_mlp(
    const float* __restrict__ xyz, const float* __restrict__ color,
    const float* __restrict__ outC, const uint32_t* __restrict__ kidx,
    const _Float16* __restrict__ sw1, const _Float16* __restrict__ sw2,
    const _Float16* __restrict__ sw3, const _Float16* __restrict__ sw4,
    const float* __restrict__ wpt,
    const float* __restrict__ b1, const float* __restrict__ b2,
    const float* __restrict__ b3, const float* __restrict__ b4,
    const float* __restrict__ bp, float* __restrict__ outE) {
  const int bi = blockIdx.x;
  const int b = (bi & 7) >> 1;
  const int g = ((bi >> 3) << 1) | (bi & 1);
  const int tid = threadIdx.x;
  const int wave = tid >> 6, lane = tid & 63;
  // bufA: X0 (stride 40, 5120B) then X2 (stride 136, 17408B)
  // bufB: X1 (stride 72, 9216B) then X3 (stride 264, 33792B)
  // maxv/psum alias bufA (X0/X2 dead by the time they're written)
  __shared__ __align__(16) char smem[17408 + 33792];
  _Float16* bufA = (_Float16*)smem;
  _Float16* bufB = (_Float16*)(smem + 17408);
  float* maxv = (float*)smem;              // 512 f32 = 2048 B
  float* psum = (float*)(smem + 2048);     // 240 f32

  if (tid < kM) {
    uint32_t p = kidx[((size_t)b * kG + g) * kM + tid];
    const float* cen = outC + ((size_t)b * kG + g) * 3;
    const float* xp = xyz + ((size_t)b * kN + p) * 3;
    const float* cp = color + ((size_t)b * kN + p) * 3;
    f16x8 v = {};
    v[0] = (_Float16)__fsub_rn(xp[0], cen[0]);
    v[1] = (_Float16)__fsub_rn(xp[1], cen[1]);
    v[2] = (_Float16)__fsub_rn(xp[2], cen[2]);
    v[3] = (_Float16)cp[0];
    v[4] = (_Float16)cp[1];
    v[5] = (_Float16)cp[2];
    f16x8 z = {};
    *(f16x8*)(bufA + tid * 40 + 0) = v;
    *(f16x8*)(bufA + tid * 40 + 8) = z;
    *(f16x8*)(bufA + tid * 40 + 16) = z;
    *(f16x8*)(bufA + tid * 40 + 24) = z;
  }
  __syncthreads();
  mfma_layer<32, 64, 40, 72>(bufA, bufB, sw1, b1, wave, lane);    // X0 -> X1
  __syncthreads();
  mfma_layer<64, 128, 72, 136>(bufB, bufA, sw2, b2, wave, lane);  // X1 -> X2
  __syncthreads();
  mfma_layer<128, 256, 136, 264>(bufA, bufB, sw3, b3, wave, lane);// X2 -> X3
  __syncthreads();
  mfma_layer4(bufB, sw4, b4, maxv, wave, lane);                   // X3 -> maxv (aliases bufA)
  __syncthreads();
  if (tid < 240) {
    int j = tid >> 2, q = tid & 3;
    const float* w = wpt + (size_t)j * 512 + q * 128;
    float s = 0.f;
#pragma unroll 4
    for (int k = 0; k < 128; ++k) s = fmaf(maxv[q * 128 + k], w[k], s);
    psum[tid] = s;
  }
  __syncthreads();
  if (tid < kE) {
    float e = __fadd_rn(__fadd_rn(psum[tid * 4 + 0], psum[tid * 4 + 1]),
                        __fadd_rn(psum[tid * 4 + 2], psum[tid * 4 + 3])) + bp[tid];
    outE[((size_t)b * kG + g) * kE + tid] = e;
  }
}

// =====================  launch  =====================
extern "C" void kernel_launch(void* const* d_in, const int* in_sizes, int n_in,
                              void* d_out, int out_size, void* d_ws, size_t ws_size,
                              hipStream_t stream) {
  (void)in_sizes; (void)n_in; (void)out_size; (void)ws_size;
  const float* xyz = (const float*)d_in[0];
  const float* color = (const float*)d_in[1];
  const float* W1 = (const float*)d_in[2];
  const float* b1 = (const float*)d_in[3];
  const float* W2 = (const float*)d_in[4];
  const float* b2 = (const float*)d_in[5];
  const float* W3 = (const float*)d_in[6];
  const float* b3 = (const float*)d_in[7];
  const float* W4 = (const float*)d_in[8];
  const float* b4 = (const float*)d_in[9];
  const float* Wp = (const float*)d_in[10];
  const float* bp = (const float*)d_in[11];

  char* ws = (char*)d_ws;
  auto win = (unsigned long long*)(ws + OFF_WIN);
  auto cnt = (unsigned int*)(ws + OFF_CNT);
  auto ccnt = (uint32_t*)(ws + OFF_CCNT);
  auto cstart = (uint32_t*)(ws + OFF_CSTART);
  auto cur = (uint32_t*)(ws + OFF_CUR);
  auto sw1 = (_Float16*)(ws + OFF_SW1);
  auto sw2 = (_Float16*)(ws + OFF_SW2);
  auto sw3 = (_Float16*)(ws + OFF_SW3);
  auto sw4 = (_Float16*)(ws + OFF_SW4);
  auto wpt = (float*)(ws + OFF_WPT);
  auto sorted = (float4*)(ws + OFF_SORT);
  auto kidx = (uint32_t*)(ws + OFF_KIDX);

  float* outE = (float*)d_out;
  float* outC = outE + (size_t)kB * kG * kE;

  k_zero<<<64, 256, 0, stream>>>((uint32_t*)ws, (int)(ZERO_BYTES / 4));
  k_prep<<<256, 256, 0, stream>>>(W1, W2, W3, W4, Wp, sw1, sw2, sw3, sw4, wpt);
  k_fps<<<kB * FPS_SUB, 1024, 0, stream>>>(xyz, outC, win, cnt);
  k_cellcount<<<512, 256, 0, stream>>>(xyz, ccnt);
  k_scan<<<kB, 256, 0, stream>>>(ccnt, cstart, cur);
  k_scatter<<<512, 256, 0, stream>>>(xyz, cur, sorted);
  k_knn<<<kB * kG, 256, 0, stream>>>(sorted, cstart, outC, kidx);
  k_mlp<<<kB * kG, 256, 0, stream>>>(xyz, color, outC, kidx, sw1, sw2, sw3, sw4, wpt,
                                     b1, b2, b3, b4, bp, outE);
}